// Round 3
// baseline (894.546 us; speedup 1.0000x reference)
//
#include <hip/hip_runtime.h>
#include <hip/hip_bf16.h>

// out[bt,o] = b[o] + sum_{i,j} Xa[bt,i]*Xb[bt,j]*W[o, i*257+j],
//   Xa=[1,X], Xb=[1,X_aux].
// Chunks c: c<256: sum_j x[bt,c]*xb[bt,j]*Bp[c][o][j]
//           c=256: sum_j xb[bt,j]*Bp[256][o][j]        (scale 1, frags Xb)
//           c=257: sum_j x[bt,j]*Bp[257][o][j]         (scale 1, frags X)
// k=0 corner W[o,0] folded into reduce with bias.
//
// R3: scale-after-MFMA. Xb fragments live in VGPRs (loaded once, reused for
// every c); per (c, j-half) a 4-deep MFMA chain computes tmp = Xb·Bp window,
// then acc += x[bt,c] * tmp in f32. No A tile in LDS at all. B double-buffered
// via global_load_lds (linear dest, pre-swizzled source, XOR-16 swizzled read).

#define DI 66049

typedef __attribute__((ext_vector_type(8))) short bf16x8;
typedef __attribute__((ext_vector_type(4))) float f32x4;

__device__ __forceinline__ unsigned short f2b(float f) {
  union { __hip_bfloat16 h; unsigned short u; } cv;
  cv.h = __float2bfloat16(f);
  return cv.u;
}

__device__ __forceinline__ bf16x8 pack8(f32x4 lo, f32x4 hi) {
  bf16x8 r;
  r[0] = (short)f2b(lo[0]); r[1] = (short)f2b(lo[1]);
  r[2] = (short)f2b(lo[2]); r[3] = (short)f2b(lo[3]);
  r[4] = (short)f2b(hi[0]); r[5] = (short)f2b(hi[1]);
  r[6] = (short)f2b(hi[2]); r[7] = (short)f2b(hi[3]);
  return r;
}

__device__ __forceinline__ void gload16(const void* g, void* l) {
  __builtin_amdgcn_global_load_lds(
      (const __attribute__((address_space(1))) unsigned int*)g,
      (__attribute__((address_space(3))) unsigned int*)l, 16, 0, 0);
}

// ---- prep: gather W (f32) into bf16 Bp[c][o][j] (linear layout), c in [0,258)
__global__ void prep_w(const float* __restrict__ W, unsigned short* __restrict__ Bp) {
  const int c = blockIdx.x;
  const int o = (blockIdx.y << 2) + (threadIdx.x >> 6);
  const int j = (threadIdx.x & 63) << 2;
  const float* wrow = W + (size_t)o * DI;
  float v0, v1, v2, v3;
  if (c < 256) {
    const int bse = (c + 1) * 257 + 1 + j;
    v0 = wrow[bse]; v1 = wrow[bse + 1]; v2 = wrow[bse + 2]; v3 = wrow[bse + 3];
  } else if (c == 256) {
    const int bse = 1 + j;
    v0 = wrow[bse]; v1 = wrow[bse + 1]; v2 = wrow[bse + 2]; v3 = wrow[bse + 3];
  } else {
    v0 = wrow[(j + 1) * 257]; v1 = wrow[(j + 2) * 257];
    v2 = wrow[(j + 3) * 257]; v3 = wrow[(j + 4) * 257];
  }
  unsigned short* dst = Bp + (((size_t)c << 8) + o) * 256 + j;
  const unsigned int lo = (unsigned int)f2b(v0) | ((unsigned int)f2b(v1) << 16);
  const unsigned int hi = (unsigned int)f2b(v2) | ((unsigned int)f2b(v3) << 16);
  *(uint2*)dst = make_uint2(lo, hi);
}

// ---- prep: Xt[c][bt] = X[bt][c]  (f32 transpose for broadcast scale loads)
__global__ void prep_xt(const float* __restrict__ X, float* __restrict__ Xt) {
  __shared__ float t[32][33];
  const int tx = threadIdx.x, ty = threadIdx.y;
  const int bt0 = blockIdx.x << 5, c0 = blockIdx.y << 5;
#pragma unroll
  for (int k = 0; k < 4; ++k) {
    const int row = (ty << 2) + k;
    t[row][tx] = X[(size_t)(bt0 + row) * 256 + c0 + tx];
  }
  __syncthreads();
#pragma unroll
  for (int k = 0; k < 4; ++k) {
    const int row = (ty << 2) + k;
    Xt[(size_t)(c0 + row) * 4096 + bt0 + tx] = t[tx][row];
  }
}

// ---- main GEMM. Tile 128 bt x 128 o, 4 waves (64x64), per-iter j-half of 128.
#define CHALF(J)                                                               \
  do {                                                                         \
    _Pragma("unroll") for (int fn = 0; fn < 4; ++fn) {                         \
      const int rowb = wc + (fn << 4) + l15;                                   \
      const unsigned short* bb = bsc + (rowb << 7);                            \
      const int rx = rowb & 15;                                                \
      bf16x8 b0 = *(const bf16x8*)(bb + (((0 + lg) ^ rx) << 3));               \
      bf16x8 b1 = *(const bf16x8*)(bb + (((4 + lg) ^ rx) << 3));               \
      bf16x8 b2 = *(const bf16x8*)(bb + (((8 + lg) ^ rx) << 3));               \
      bf16x8 b3 = *(const bf16x8*)(bb + (((12 + lg) ^ rx) << 3));              \
      _Pragma("unroll") for (int fm = 0; fm < 4; ++fm) {                       \
        f32x4 t = {0.f, 0.f, 0.f, 0.f};                                        \
        t = __builtin_amdgcn_mfma_f32_16x16x32_bf16(xb[fm][(J)*4 + 0], b0, t,  \
                                                    0, 0, 0);                  \
        t = __builtin_amdgcn_mfma_f32_16x16x32_bf16(xb[fm][(J)*4 + 1], b1, t,  \
                                                    0, 0, 0);                  \
        t = __builtin_amdgcn_mfma_f32_16x16x32_bf16(xb[fm][(J)*4 + 2], b2, t,  \
                                                    0, 0, 0);                  \
        t = __builtin_amdgcn_mfma_f32_16x16x32_bf16(xb[fm][(J)*4 + 3], b3, t,  \
                                                    0, 0, 0);                  \
        acc[fm][fn] += s4[fm] * t;                                             \
      }                                                                        \
    }                                                                          \
  } while (0)

__global__ __launch_bounds__(256, 2) void gemm_main(
    const float* __restrict__ Xt, const float* __restrict__ X,
    const float* __restrict__ Xa, const unsigned short* __restrict__ Bp,
    float* __restrict__ P) {
  __shared__ __align__(16) unsigned short Bs[2][128 * 128];

  const int tid = threadIdx.x;
  const int S_ = gridDim.z - 1;  // main split count; bz==S_ is the c=257 slice
  // XCD-clustering swizzle (bijective: total blocks = 64*(S_+1), %8==0)
  const int total = 64 * (S_ + 1);
  const int rid = blockIdx.x + 32 * (blockIdx.y + 2 * blockIdx.z);
  const int w = (rid & 7) * (total >> 3) + (rid >> 3);
  const int bx = w & 31, g = w >> 5, by = g & 1, bz = g >> 1;

  const int bt0 = bx << 7, o0 = by << 7;
  int c0, ccnt;
  if (bz == S_) {
    c0 = 257; ccnt = 1;
  } else {
    const int q = 257 / S_, r = 257 % S_;
    c0 = bz * q + (bz < r ? bz : r);
    ccnt = q + (bz < r ? 1 : 0);
  }
  const int nIt = ccnt << 1;
  const float* xsrc = (bz == S_) ? X : Xa;

  const int wid = tid >> 6, lane = tid & 63;
  const int wr = (wid >> 1) << 6, wc = (wid & 1) << 6;
  const int l15 = lane & 15, lg = lane >> 4;

  // ---- load row fragments into registers (reused for every chunk c)
  bf16x8 xb[4][8];
#pragma unroll
  for (int fm = 0; fm < 4; ++fm) {
    const float* rp = xsrc + (size_t)(bt0 + wr + (fm << 4) + l15) * 256 + (lg << 3);
#pragma unroll
    for (int kw = 0; kw < 8; ++kw) {
      f32x4 lo = *(const f32x4*)(rp + (kw << 5));
      f32x4 hi = *(const f32x4*)(rp + (kw << 5) + 4);
      xb[fm][kw] = pack8(lo, hi);
    }
  }

  f32x4 acc[4][4] = {};
  f32x4 s4[4];

  auto STAGE = [&](int buf, int it) {
    const int c = c0 + (it >> 1), jh = it & 1;
#pragma unroll
    for (int q2 = 0; q2 < 8; ++q2) {
      const int idx = (q2 << 8) + tid;
      const int row = idx >> 4;
      const int lsl = (tid & 15) ^ (row & 15);
      const unsigned short* src =
          Bp + ((size_t)c * 256 + o0 + row) * 256 + (jh << 7) + (lsl << 3);
      gload16(src, &Bs[buf][idx << 3]);
    }
  };

  STAGE(0, 0);
  int cur = 0;

  for (int it = 0; it < nIt; ++it) {
    const int c = c0 + (it >> 1);
    const int jh = it & 1;
    __syncthreads();  // drains prev-iter stage (vmcnt) + protects buf reuse
    if (it + 1 < nIt) STAGE(cur ^ 1, it + 1);
    if (jh == 0) {
      if (c < 256) {
#pragma unroll
        for (int fm = 0; fm < 4; ++fm)
          s4[fm] = *(const f32x4*)(Xt + (size_t)c * 4096 + bt0 + wr + (fm << 4) +
                                   (lg << 2));
      } else {
#pragma unroll
        for (int fm = 0; fm < 4; ++fm) s4[fm] = (f32x4){1.f, 1.f, 1.f, 1.f};
      }
    }
    const unsigned short* bsc = Bs[cur];
    if (jh == 0) CHALF(0); else CHALF(1);
    cur ^= 1;
  }

  // ---- epilogue: C layout col = lane&15, row = (lane>>4)*4 + reg
  float* pp = P + (size_t)bz * 1048576;
#pragma unroll
  for (int fm = 0; fm < 4; ++fm) {
    const int row = bt0 + wr + (fm << 4) + (lg << 2);
#pragma unroll
    for (int fn = 0; fn < 4; ++fn) {
      const int col = o0 + wc + (fn << 4) + l15;
#pragma unroll
      for (int e = 0; e < 4; ++e)
        pp[(size_t)(row + e) * 256 + col] = acc[fm][fn][e];
    }
  }
}

// ---- reduce: sum nsl partial slices + bias + W[o,0]
__global__ void reduce_k(const float* __restrict__ P, const float* __restrict__ W,
                         const float* __restrict__ b, float* __restrict__ out,
                         int nsl) {
  const int idx = blockIdx.x * 256 + threadIdx.x;
  const int o = idx & 255;
  float v = b[o] + W[(size_t)o * DI];
  for (int s = 0; s < nsl; ++s) v += P[idx + (size_t)s * 1048576];
  out[idx] = v;
}

// ================= fallback path (tiny ws): round-2 proven kernel ============
__global__ void init_k(const float* __restrict__ W, const float* __restrict__ b,
                       float* __restrict__ out) {
  const int idx = blockIdx.x * 256 + threadIdx.x;
  const int o = idx & 255;
  out[idx] = b[o] + W[(size_t)o * DI];
}

__global__ __launch_bounds__(256, 4) void gemm_fb(
    const float* __restrict__ X, const float* __restrict__ Xa,
    const float* __restrict__ W, float* __restrict__ Out) {
  __shared__ __align__(16) unsigned short As[128 * 64];
  __shared__ __align__(16) unsigned short Bs[128 * 64];
  const int tid = threadIdx.x;
  const int bx = blockIdx.x, by = blockIdx.y, bz = blockIdx.z;
  const int S = gridDim.z;
  const int bt0 = bx << 7, o0 = by << 7;
  const int q = 258 / S, r = 258 % S;
  const int c0 = bz * q + (bz < r ? bz : r);
  const int ccnt = q + (bz < r ? 1 : 0);
  const int nK = ccnt << 2;
  const int wid = tid >> 6, lane = tid & 63;
  const int wr = (wid >> 1) << 6, wc = (wid & 1) << 6;
  const int ar = tid >> 1;
  const int ah = (tid & 1) << 5;
  const float* xrow = X + (size_t)(bt0 + ar) * 256;
  const float* varow = Xa + (size_t)(bt0 + ar) * 256;
  f32x4 acc[4][4] = {};
  for (int kt = 0; kt < nK; ++kt) {
    const int c = c0 + (kt >> 2);
    const int j0 = (kt & 3) << 6;
    __syncthreads();
    {
      const float* vs = (c == 257) ? xrow : varow;
      float s = 1.0f;
      if (c < 256) s = xrow[c];
      const f32x4* vp = (const f32x4*)(vs + j0 + ah);
      f32x4 v[8];
#pragma unroll
      for (int qq = 0; qq < 8; ++qq) v[qq] = vp[qq];
      unsigned short* aw = As + ar * 64;
      const int sl0 = ah >> 3, sx = ar & 7;
#pragma unroll
      for (int w = 0; w < 4; ++w) {
        bf16x8 pk;
#pragma unroll
        for (int e = 0; e < 8; ++e)
          pk[e] = (short)f2b(s * v[w * 2 + (e >> 2)][e & 3]);
        *(bf16x8*)(aw + (((sl0 + w) ^ sx) << 3)) = pk;
      }
    }
    {
      const int orow = tid >> 1;
      const int jh = (tid & 1) << 5;
      const float* wrow = W + (size_t)(o0 + orow) * DI;
      float tmp[32];
      if (c < 256) {
        const int bse = (c + 1) * 257 + 1 + j0 + jh;
#pragma unroll
        for (int i = 0; i < 32; ++i) tmp[i] = wrow[bse + i];
      } else if (c == 256) {
        const int bse = 1 + j0 + jh;
#pragma unroll
        for (int i = 0; i < 32; ++i) tmp[i] = wrow[bse + i];
      } else {
#pragma unroll
        for (int i = 0; i < 32; ++i) tmp[i] = wrow[(j0 + jh + i + 1) * 257];
      }
      unsigned short* bw = Bs + orow * 64;
      const int sl0 = jh >> 3, sx = orow & 7;
#pragma unroll
      for (int w = 0; w < 4; ++w) {
        bf16x8 pk;
#pragma unroll
        for (int e = 0; e < 8; ++e) pk[e] = (short)f2b(tmp[w * 8 + e]);
        *(bf16x8*)(bw + (((sl0 + w) ^ sx) << 3)) = pk;
      }
    }
    __syncthreads();
#pragma unroll
    for (int kk = 0; kk < 2; ++kk) {
      const int kslot = (kk << 2) + (lane >> 4);
      bf16x8 af[4], bfr[4];
#pragma unroll
      for (int fm = 0; fm < 4; ++fm) {
        const int row = wr + (fm << 4) + (lane & 15);
        af[fm] = *(const bf16x8*)(As + row * 64 + ((kslot ^ (row & 7)) << 3));
      }
#pragma unroll
      for (int fn = 0; fn < 4; ++fn) {
        const int row = wc + (fn << 4) + (lane & 15);
        bfr[fn] = *(const bf16x8*)(Bs + row * 64 + ((kslot ^ (row & 7)) << 3));
      }
#pragma unroll
      for (int fm = 0; fm < 4; ++fm)
#pragma unroll
        for (int fn = 0; fn < 4; ++fn)
          acc[fm][fn] = __builtin_amdgcn_mfma_f32_16x16x32_bf16(
              af[fm], bfr[fn], acc[fm][fn], 0, 0, 0);
    }
  }
  const int r0 = (lane >> 4) << 2;
  const int cl = lane & 15;
#pragma unroll
  for (int fm = 0; fm < 4; ++fm) {
    const int row = bt0 + wr + (fm << 4) + r0;
#pragma unroll
    for (int fn = 0; fn < 4; ++fn) {
      const int col = o0 + wc + (fn << 4) + cl;
#pragma unroll
      for (int rr = 0; rr < 4; ++rr)
        atomicAdd(Out + (size_t)(row + rr) * 256 + col, acc[fm][fn][rr]);
    }
  }
}

extern "C" void kernel_launch(void* const* d_in, const int* in_sizes, int n_in,
                              void* d_out, int out_size, void* d_ws, size_t ws_size,
                              hipStream_t stream) {
  const float* X  = (const float*)d_in[0];
  const float* Xa = (const float*)d_in[1];
  const float* W  = (const float*)d_in[2];
  const float* b  = (const float*)d_in[3];
  float* out = (float*)d_out;

  const size_t WBF_SZ = (size_t)258 * 256 * 256 * 2;  // 33,816,576 B
  const size_t XT_SZ  = (size_t)256 * 4096 * 4;       //  4,194,304 B
  const size_t PART1  = (size_t)4096 * 256 * 4;       //  4 MiB per slice

  int S = 0;
  for (int cand : {8, 4, 2})
    if (ws_size >= WBF_SZ + XT_SZ + (size_t)(cand + 1) * PART1) { S = cand; break; }

  if (S > 0) {
    unsigned short* Bp = (unsigned short*)d_ws;
    float* Xt = (float*)((char*)d_ws + WBF_SZ);
    float* P  = (float*)((char*)d_ws + WBF_SZ + XT_SZ);
    prep_w<<<dim3(258, 64), 256, 0, stream>>>(W, Bp);
    prep_xt<<<dim3(128, 8), dim3(32, 8), 0, stream>>>(X, Xt);
    gemm_main<<<dim3(32, 2, S + 1), 256, 0, stream>>>(Xt, X, Xa, Bp, P);
    reduce_k<<<4096, 256, 0, stream>>>(P, W, b, out, S + 1);
  } else {
    init_k<<<4096, 256, 0, stream>>>(W, b, out);
    gemm_fb<<<dim3(32, 2, 4), 256, 0, stream>>>(X, Xa, W, out);
  }
}

// Round 4
// 273.683 us; speedup vs baseline: 3.2685x; 3.2685x over previous
//
#include <hip/hip_runtime.h>
#include <hip/hip_bf16.h>

// out[bt,o] = b[o] + sum_{i,j} Xa[bt,i]*Xb[bt,j]*W[o, i*257+j], Xa=[1,X], Xb=[1,X_aux]
// Chunk decomposition (c in [0,258)):
//   c<256 : A[r,j] = X[r,c]*X_aux[r,j],  Bp[c][o][j] = W[o,(c+1)*257+1+j]
//   c=256 : A[r,j] = X_aux[r,j],         Bp[c][o][j] = W[o,1+j]
//   c=257 : A[r,j] = X[r,j],             Bp[c][o][j] = W[o,(j+1)*257]
// k=0 corner (W[o,0]) folded into reduce with bias.
//
// R4: m201-style 8-phase 256x256 tile, BK=64, 8 waves (wave = 128bt x 64o),
// 128KB dbuf LDS, XOR-8 slot swizzle (proven 0-conflict in R2), A-half
// VALU-generated (rank-1), B-half via global_load_lds (linear dest,
// pre-swizzled source). Split-K S=16 -> 256 blocks = 1/CU. Drain vmcnt only
// at phases 4/8 (3-phase issue lead). setprio around MFMA clusters.

#define DI 66049

typedef __attribute__((ext_vector_type(8))) short bf16x8;
typedef __attribute__((ext_vector_type(4))) float f32x4;

__device__ __forceinline__ unsigned short f2b(float f) {
  union { __hip_bfloat16 h; unsigned short u; } cv;
  cv.h = __float2bfloat16(f);
  return cv.u;
}

__device__ __forceinline__ bf16x8 pack8(f32x4 lo, f32x4 hi) {
  bf16x8 r;
  r[0] = (short)f2b(lo[0]); r[1] = (short)f2b(lo[1]);
  r[2] = (short)f2b(lo[2]); r[3] = (short)f2b(lo[3]);
  r[4] = (short)f2b(hi[0]); r[5] = (short)f2b(hi[1]);
  r[6] = (short)f2b(hi[2]); r[7] = (short)f2b(hi[3]);
  return r;
}

__device__ __forceinline__ void gload16(const void* g, void* l) {
  __builtin_amdgcn_global_load_lds(
      (const __attribute__((address_space(1))) unsigned int*)g,
      (__attribute__((address_space(3))) unsigned int*)l, 16, 0, 0);
}

// ---- prep: gather W (f32) into bf16 Bp[c][o][j] (linear), c in [0,258)
__global__ void prep_w(const float* __restrict__ W, unsigned short* __restrict__ Bp) {
  const int c = blockIdx.x;
  const int o = (blockIdx.y << 2) + (threadIdx.x >> 6);
  const int j = (threadIdx.x & 63) << 2;
  const float* wrow = W + (size_t)o * DI;
  float v0, v1, v2, v3;
  if (c < 256) {
    const int bse = (c + 1) * 257 + 1 + j;
    v0 = wrow[bse]; v1 = wrow[bse + 1]; v2 = wrow[bse + 2]; v3 = wrow[bse + 3];
  } else if (c == 256) {
    const int bse = 1 + j;
    v0 = wrow[bse]; v1 = wrow[bse + 1]; v2 = wrow[bse + 2]; v3 = wrow[bse + 3];
  } else {
    v0 = wrow[(j + 1) * 257]; v1 = wrow[(j + 2) * 257];
    v2 = wrow[(j + 3) * 257]; v3 = wrow[(j + 4) * 257];
  }
  unsigned short* dst = Bp + (((size_t)c << 8) + o) * 256 + j;
  const unsigned int lo = (unsigned int)f2b(v0) | ((unsigned int)f2b(v1) << 16);
  const unsigned int hi = (unsigned int)f2b(v2) | ((unsigned int)f2b(v3) << 16);
  *(uint2*)dst = make_uint2(lo, hi);
}

// ---- 8-phase GEMM: 256bt x 256o per block, 512 threads (8 waves 2x4)
#define PHASE(BUF, FH, KH, STAGE)                                              \
  {                                                                            \
    bf16x8 _af[4], _bf[4];                                                     \
    const int _slot = ((KH) << 2) + lg;                                        \
    _Pragma("unroll") for (int _i = 0; _i < 4; ++_i) {                         \
      const int _ra = (wm << 7) + (((FH) << 2) + _i) * 16 + l15;               \
      _af[_i] = *(const bf16x8*)(&As[BUF][_ra * 64 + ((_slot ^ (_ra & 7)) << 3)]); \
      const int _rb = (wn << 6) + (_i << 4) + l15;                             \
      _bf[_i] = *(const bf16x8*)(&Bs[BUF][_rb * 64 + ((_slot ^ (_rb & 7)) << 3)]); \
    }                                                                          \
    STAGE;                                                                     \
    __builtin_amdgcn_s_barrier();                                              \
    asm volatile("s_waitcnt lgkmcnt(0)" ::: "memory");                         \
    __builtin_amdgcn_sched_barrier(0);                                         \
    __builtin_amdgcn_s_setprio(1);                                             \
    _Pragma("unroll") for (int _i = 0; _i < 4; ++_i)                           \
      _Pragma("unroll") for (int _fn = 0; _fn < 4; ++_fn)                      \
        acc[((FH) << 2) + _i][_fn] = __builtin_amdgcn_mfma_f32_16x16x32_bf16(  \
            _af[_i], _bf[_fn], acc[((FH) << 2) + _i][_fn], 0, 0, 0);           \
    __builtin_amdgcn_s_setprio(0);                                             \
    __builtin_amdgcn_s_barrier();                                              \
  }

__global__ __launch_bounds__(512, 2) void gemm8(
    const float* __restrict__ X, const float* __restrict__ Xa,
    const unsigned short* __restrict__ Bp, float* __restrict__ P) {
  __shared__ __align__(16) unsigned short As[2][256 * 64];
  __shared__ __align__(16) unsigned short Bs[2][256 * 64];

  const int tid = threadIdx.x;
  const int nwg = gridDim.x;
  const int S = nwg >> 4;

  // bijective XCD-cluster swizzle (m204): consecutive w -> same slice
  const int rid = blockIdx.x;
  const int qx = nwg >> 3, rx = nwg & 7;
  const int xcd = rid & 7, sidx = rid >> 3;
  const int w = (xcd < rx ? xcd * (qx + 1) : rx * (qx + 1) + (xcd - rx) * qx) + sidx;
  const int bz = w >> 4, bx = w & 15;
  const int bt0 = bx << 8;

  const int q2 = 258 / S, r2 = 258 % S;
  const int c0 = bz * q2 + (bz < r2 ? bz : r2);
  const int ccnt = q2 + (bz < r2 ? 1 : 0);
  const int nKt = ccnt << 2;  // BK=64 tiles; always even

  const int wid = tid >> 6, lane = tid & 63;
  const int wm = wid >> 2, wn = wid & 3;
  const int l15 = lane & 15, lg = lane >> 4;
  const int arow = tid >> 2, jq = tid & 3;  // A-gen: 4 threads/row

  f32x4 acc[8][4] = {};
  f32x4 av[2][4];
  float s0 = 1.f, s1 = 1.f;

  auto ISSUE_A = [&](int kt) {  // issue A f32 loads + scale loads (early)
    const int c = c0 + (kt >> 2);
    const int jb = (kt & 3) << 6;
    const float* src = (c == 257) ? X : Xa;
#pragma unroll
    for (int h = 0; h < 2; ++h) {
      const float* p = src + (size_t)(bt0 + (h << 7) + arow) * 256 + jb + (jq << 4);
#pragma unroll
      for (int q = 0; q < 4; ++q) av[h][q] = *(const f32x4*)(p + (q << 2));
    }
    if (c < 256) {
      s0 = X[(size_t)(bt0 + arow) * 256 + c];
      s1 = X[(size_t)(bt0 + 128 + arow) * 256 + c];
    } else {
      s0 = 1.f; s1 = 1.f;
    }
  };

  auto STAGE_B = [&](int kt, int buf) {  // 4 x gload16/thread, linear dest
    const int c = c0 + (kt >> 2);
    const int jb = (kt & 3) << 6;
#pragma unroll
    for (int e = 0; e < 4; ++e) {
      const int rbase = (wid << 5) + (e << 3);
      const int orow = rbase + (lane >> 3);
      const int sl = (lane & 7) ^ (orow & 7);  // pre-swizzled source
      const unsigned short* src =
          Bp + ((size_t)c * 256 + orow) * 256 + jb + (sl << 3);
      gload16(src, &Bs[buf][rbase << 6]);
    }
  };

  auto PACK_A = [&](int h, int buf) {  // consume av -> scaled bf16 -> LDS
    const float s = h ? s1 : s0;
    const int row = (h << 7) + arow;
    const int sx = row & 7;
    f32x4 m0 = s * av[h][0], m1 = s * av[h][1];
    f32x4 m2 = s * av[h][2], m3 = s * av[h][3];
    *(bf16x8*)(&As[buf][row * 64 + ((((jq << 1) | 0) ^ sx) << 3)]) = pack8(m0, m1);
    *(bf16x8*)(&As[buf][row * 64 + ((((jq << 1) | 1) ^ sx) << 3)]) = pack8(m2, m3);
  };

  // ---- prologue: fully stage kt=0 into buf0
  ISSUE_A(0);
  STAGE_B(0, 0);
  PACK_A(0, 0);
  PACK_A(1, 0);
  asm volatile("s_waitcnt vmcnt(0)" ::: "memory");
  __syncthreads();

  // ---- main loop: 2 K-tiles per iteration, 8 phases
  for (int kt = 0; kt < nKt; kt += 2) {
    const bool h2 = (kt + 2) < nKt;
    PHASE(0, 0, 0, { ISSUE_A(kt + 1); STAGE_B(kt + 1, 1); });
    PHASE(0, 0, 1, { PACK_A(0, 1); });
    PHASE(0, 1, 0, { PACK_A(1, 1); });
    PHASE(0, 1, 1, { asm volatile("s_waitcnt vmcnt(0)" ::: "memory"); });
    PHASE(1, 0, 0, { if (h2) { ISSUE_A(kt + 2); STAGE_B(kt + 2, 0); } });
    PHASE(1, 0, 1, { if (h2) PACK_A(0, 0); });
    PHASE(1, 1, 0, { if (h2) PACK_A(1, 0); });
    PHASE(1, 1, 1, { asm volatile("s_waitcnt vmcnt(0)" ::: "memory"); });
  }

  // ---- epilogue: C layout col = lane&15, row = (lane>>4)*4 + reg
  float* pp = P + ((size_t)bz << 20);
#pragma unroll
  for (int fm = 0; fm < 8; ++fm) {
    const int row = bt0 + (wm << 7) + (fm << 4) + (lg << 2);
#pragma unroll
    for (int fn = 0; fn < 4; ++fn) {
      const int col = (wn << 6) + (fn << 4) + l15;
#pragma unroll
      for (int e = 0; e < 4; ++e)
        pp[(size_t)(row + e) * 256 + col] = acc[fm][fn][e];
    }
  }
}

// ---- reduce: sum S partial slices + bias + W[o,0]
__global__ void reduce_k(const float* __restrict__ P, const float* __restrict__ W,
                         const float* __restrict__ b, float* __restrict__ out,
                         int nsl) {
  const int idx = blockIdx.x * 256 + threadIdx.x;
  const int o = idx & 255;
  float v = b[o] + W[(size_t)o * DI];
  for (int s = 0; s < nsl; ++s) v += P[idx + (size_t)s * 1048576];
  out[idx] = v;
}

// ================= fallback path (tiny ws): R2 proven kernels ================
__global__ void init_k(const float* __restrict__ W, const float* __restrict__ b,
                       float* __restrict__ out) {
  const int idx = blockIdx.x * 256 + threadIdx.x;
  const int o = idx & 255;
  out[idx] = b[o] + W[(size_t)o * DI];
}

__global__ __launch_bounds__(256, 4) void gemm_fb(
    const float* __restrict__ X, const float* __restrict__ Xa,
    const float* __restrict__ W, float* __restrict__ Out) {
  __shared__ __align__(16) unsigned short As[128 * 64];
  __shared__ __align__(16) unsigned short Bs[128 * 64];
  const int tid = threadIdx.x;
  const int bx = blockIdx.x, by = blockIdx.y, bz = blockIdx.z;
  const int S = gridDim.z;
  const int bt0 = bx << 7, o0 = by << 7;
  const int q = 258 / S, r = 258 % S;
  const int c0 = bz * q + (bz < r ? bz : r);
  const int ccnt = q + (bz < r ? 1 : 0);
  const int nK = ccnt << 2;
  const int wid = tid >> 6, lane = tid & 63;
  const int wr = (wid >> 1) << 6, wc = (wid & 1) << 6;
  const int ar = tid >> 1;
  const int ah = (tid & 1) << 5;
  const float* xrow = X + (size_t)(bt0 + ar) * 256;
  const float* varow = Xa + (size_t)(bt0 + ar) * 256;
  f32x4 acc[4][4] = {};
  for (int kt = 0; kt < nK; ++kt) {
    const int c = c0 + (kt >> 2);
    const int j0 = (kt & 3) << 6;
    __syncthreads();
    {
      const float* vs = (c == 257) ? xrow : varow;
      float s = 1.0f;
      if (c < 256) s = xrow[c];
      const f32x4* vp = (const f32x4*)(vs + j0 + ah);
      f32x4 v[8];
#pragma unroll
      for (int qq = 0; qq < 8; ++qq) v[qq] = vp[qq];
      unsigned short* aw = As + ar * 64;
      const int sl0 = ah >> 3, sx = ar & 7;
#pragma unroll
      for (int w = 0; w < 4; ++w) {
        bf16x8 pk;
#pragma unroll
        for (int e = 0; e < 8; ++e)
          pk[e] = (short)f2b(s * v[w * 2 + (e >> 2)][e & 3]);
        *(bf16x8*)(aw + (((sl0 + w) ^ sx) << 3)) = pk;
      }
    }
    {
      const int orow = tid >> 1;
      const int jh = (tid & 1) << 5;
      const float* wrow = W + (size_t)(o0 + orow) * DI;
      float tmp[32];
      if (c < 256) {
        const int bse = (c + 1) * 257 + 1 + j0 + jh;
#pragma unroll
        for (int i = 0; i < 32; ++i) tmp[i] = wrow[bse + i];
      } else if (c == 256) {
        const int bse = 1 + j0 + jh;
#pragma unroll
        for (int i = 0; i < 32; ++i) tmp[i] = wrow[bse + i];
      } else {
#pragma unroll
        for (int i = 0; i < 32; ++i) tmp[i] = wrow[(j0 + jh + i + 1) * 257];
      }
      unsigned short* bw = Bs + orow * 64;
      const int sl0 = jh >> 3, sx = orow & 7;
#pragma unroll
      for (int w = 0; w < 4; ++w) {
        bf16x8 pk;
#pragma unroll
        for (int e = 0; e < 8; ++e) pk[e] = (short)f2b(tmp[w * 8 + e]);
        *(bf16x8*)(bw + (((sl0 + w) ^ sx) << 3)) = pk;
      }
    }
    __syncthreads();
#pragma unroll
    for (int kk = 0; kk < 2; ++kk) {
      const int kslot = (kk << 2) + (lane >> 4);
      bf16x8 af[4], bfr[4];
#pragma unroll
      for (int fm = 0; fm < 4; ++fm) {
        const int row = wr + (fm << 4) + (lane & 15);
        af[fm] = *(const bf16x8*)(As + row * 64 + ((kslot ^ (row & 7)) << 3));
      }
#pragma unroll
      for (int fn = 0; fn < 4; ++fn) {
        const int row = wc + (fn << 4) + (lane & 15);
        bfr[fn] = *(const bf16x8*)(Bs + row * 64 + ((kslot ^ (row & 7)) << 3));
      }
#pragma unroll
      for (int fm = 0; fm < 4; ++fm)
#pragma unroll
        for (int fn = 0; fn < 4; ++fn)
          acc[fm][fn] = __builtin_amdgcn_mfma_f32_16x16x32_bf16(
              af[fm], bfr[fn], acc[fm][fn], 0, 0, 0);
    }
  }
  const int r0 = (lane >> 4) << 2;
  const int cl = lane & 15;
#pragma unroll
  for (int fm = 0; fm < 4; ++fm) {
    const int row = bt0 + wr + (fm << 4) + r0;
#pragma unroll
    for (int fn = 0; fn < 4; ++fn) {
      const int col = o0 + wc + (fn << 4) + cl;
#pragma unroll
      for (int rr = 0; rr < 4; ++rr)
        atomicAdd(Out + (size_t)(row + rr) * 256 + col, acc[fm][fn][rr]);
    }
  }
}

extern "C" void kernel_launch(void* const* d_in, const int* in_sizes, int n_in,
                              void* d_out, int out_size, void* d_ws, size_t ws_size,
                              hipStream_t stream) {
  const float* X  = (const float*)d_in[0];
  const float* Xa = (const float*)d_in[1];
  const float* W  = (const float*)d_in[2];
  const float* b  = (const float*)d_in[3];
  float* out = (float*)d_out;

  const size_t WBF_SZ = (size_t)258 * 256 * 256 * 2;  // 33,816,576 B
  const size_t PART1  = (size_t)4096 * 256 * 4;       // 4 MiB per slice

  int S = 0;
  if (ws_size > WBF_SZ) {
    size_t fit = (ws_size - WBF_SZ) / PART1;
    S = (int)(fit < 16 ? fit : 16);
  }

  if (S >= 2) {
    unsigned short* Bp = (unsigned short*)d_ws;
    float* P = (float*)((char*)d_ws + WBF_SZ);
    prep_w<<<dim3(258, 64), 256, 0, stream>>>(W, Bp);
    gemm8<<<dim3(16 * S), 512, 0, stream>>>(X, Xa, Bp, P);
    reduce_k<<<4096, 256, 0, stream>>>(P, W, b, out, S);
  } else {
    init_k<<<4096, 256, 0, stream>>>(W, b, out);
    gemm_fb<<<dim3(32, 2, 4), 256, 0, stream>>>(X, Xa, W, out);
  }
}

// Round 5
// 254.314 us; speedup vs baseline: 3.5175x; 1.0762x over previous
//
#include <hip/hip_runtime.h>
#include <hip/hip_bf16.h>

// out[bt,o] = b[o] + sum_{i,j} Xa[bt,i]*Xb[bt,j]*W[o, i*257+j], Xa=[1,X], Xb=[1,X_aux]
// Chunk decomposition (c in [0,258)):
//   c<256 : A[r,j] = X[r,c]*X_aux[r,j],  Bp[c][o][j] = W[o,(c+1)*257+1+j]
//   c=256 : A[r,j] = X_aux[r,j],         Bp[c][o][j] = W[o,1+j]
//   c=257 : A[r,j] = X[r,j],             Bp[c][o][j] = W[o,(j+1)*257]
// k=0 corner (W[o,0]) folded into reduce with bias.
//
// R5: deep-pipelined 8-phase 256x256 tile. av register slabs double-buffered
// (4-6 phase load lead), scales via transposed Xt (issued P1, used P3/P6),
// bf fragments read once per KH (24 ds_read_b128 / K-tile), counted vmcnt(8)
// at phases 4/8 only (loads stay in flight across barriers).

#define DI 66049

typedef __attribute__((ext_vector_type(8))) short bf16x8;
typedef __attribute__((ext_vector_type(4))) float f32x4;

__device__ __forceinline__ unsigned short f2b(float f) {
  union { __hip_bfloat16 h; unsigned short u; } cv;
  cv.h = __float2bfloat16(f);
  return cv.u;
}

__device__ __forceinline__ bf16x8 pack8(f32x4 lo, f32x4 hi) {
  bf16x8 r;
  r[0] = (short)f2b(lo[0]); r[1] = (short)f2b(lo[1]);
  r[2] = (short)f2b(lo[2]); r[3] = (short)f2b(lo[3]);
  r[4] = (short)f2b(hi[0]); r[5] = (short)f2b(hi[1]);
  r[6] = (short)f2b(hi[2]); r[7] = (short)f2b(hi[3]);
  return r;
}

__device__ __forceinline__ void gload16(const void* g, void* l) {
  __builtin_amdgcn_global_load_lds(
      (const __attribute__((address_space(1))) unsigned int*)g,
      (__attribute__((address_space(3))) unsigned int*)l, 16, 0, 0);
}

// ---- prep: gather W (f32) into bf16 Bp[c][o][j] (linear), c in [0,258)
__global__ void prep_w(const float* __restrict__ W, unsigned short* __restrict__ Bp) {
  const int c = blockIdx.x;
  const int o = (blockIdx.y << 2) + (threadIdx.x >> 6);
  const int j = (threadIdx.x & 63) << 2;
  const float* wrow = W + (size_t)o * DI;
  float v0, v1, v2, v3;
  if (c < 256) {
    const int bse = (c + 1) * 257 + 1 + j;
    v0 = wrow[bse]; v1 = wrow[bse + 1]; v2 = wrow[bse + 2]; v3 = wrow[bse + 3];
  } else if (c == 256) {
    const int bse = 1 + j;
    v0 = wrow[bse]; v1 = wrow[bse + 1]; v2 = wrow[bse + 2]; v3 = wrow[bse + 3];
  } else {
    v0 = wrow[(j + 1) * 257]; v1 = wrow[(j + 2) * 257];
    v2 = wrow[(j + 3) * 257]; v3 = wrow[(j + 4) * 257];
  }
  unsigned short* dst = Bp + (((size_t)c << 8) + o) * 256 + j;
  const unsigned int lo = (unsigned int)f2b(v0) | ((unsigned int)f2b(v1) << 16);
  const unsigned int hi = (unsigned int)f2b(v2) | ((unsigned int)f2b(v3) << 16);
  *(uint2*)dst = make_uint2(lo, hi);
}

// ---- prep: Xt[c][bt] = X[bt][c]  (f32 transpose for coalesced scale loads)
__global__ void prep_xt(const float* __restrict__ X, float* __restrict__ Xt) {
  __shared__ float t[32][33];
  const int tx = threadIdx.x, ty = threadIdx.y;
  const int bt0 = blockIdx.x << 5, c0 = blockIdx.y << 5;
#pragma unroll
  for (int k = 0; k < 4; ++k) {
    const int row = (ty << 2) + k;
    t[row][tx] = X[(size_t)(bt0 + row) * 256 + c0 + tx];
  }
  __syncthreads();
#pragma unroll
  for (int k = 0; k < 4; ++k) {
    const int row = (ty << 2) + k;
    Xt[(size_t)(c0 + row) * 4096 + bt0 + tx] = t[tx][row];
  }
}

// ---- phase macro: ds_reads -> STAGE -> bar -> lgkm0 -> 16 MFMA -> POST -> bar
#define PHASE(BUF, FH, KH, RB, STAGE, POST)                                    \
  {                                                                            \
    const int _slot = ((KH) << 2) + lg;                                        \
    if (RB) {                                                                  \
      _Pragma("unroll") for (int _i = 0; _i < 4; ++_i) {                       \
        const int _rb = (wn << 6) + (_i << 4) + l15;                           \
        bfr[_i] =                                                              \
            *(const bf16x8*)(&Bs[BUF][_rb * 64 + ((_slot ^ (_rb & 7)) << 3)]); \
      }                                                                        \
    }                                                                          \
    bf16x8 _af[4];                                                             \
    _Pragma("unroll") for (int _i = 0; _i < 4; ++_i) {                         \
      const int _ra = (wm << 7) + (((FH) << 2) + _i) * 16 + l15;               \
      _af[_i] =                                                                \
          *(const bf16x8*)(&As[BUF][_ra * 64 + ((_slot ^ (_ra & 7)) << 3)]);   \
    }                                                                          \
    STAGE;                                                                     \
    __builtin_amdgcn_s_barrier();                                              \
    asm volatile("s_waitcnt lgkmcnt(0)" ::: "memory");                         \
    __builtin_amdgcn_sched_barrier(0);                                         \
    __builtin_amdgcn_s_setprio(1);                                             \
    _Pragma("unroll") for (int _i = 0; _i < 4; ++_i)                           \
      _Pragma("unroll") for (int _fn = 0; _fn < 4; ++_fn)                      \
        acc[((FH) << 2) + _i][_fn] = __builtin_amdgcn_mfma_f32_16x16x32_bf16(  \
            _af[_i], bfr[_fn], acc[((FH) << 2) + _i][_fn], 0, 0, 0);           \
    __builtin_amdgcn_s_setprio(0);                                             \
    POST;                                                                      \
    __builtin_amdgcn_s_barrier();                                              \
  }

#define ISSUE_A(KT, AV)                                                        \
  {                                                                            \
    const int _c = c0 + ((KT) >> 2);                                           \
    const int _jb = ((KT) & 3) << 6;                                           \
    const float* _src = (_c == 257) ? X : Xa;                                  \
    const float* _p = _src + (size_t)(bt0 + arow) * 256 + _jb + (jq << 4);     \
    _Pragma("unroll") for (int _q = 0; _q < 4; ++_q)                           \
        AV[0][_q] = *(const f32x4*)(_p + (_q << 2));                           \
    const float* _p2 =                                                         \
        _src + (size_t)(bt0 + 128 + arow) * 256 + _jb + (jq << 4);             \
    _Pragma("unroll") for (int _q = 0; _q < 4; ++_q)                           \
        AV[1][_q] = *(const f32x4*)(_p2 + (_q << 2));                          \
  }

#define LOAD_S(KT, S0, S1)                                                     \
  {                                                                            \
    const int _c = c0 + ((KT) >> 2);                                           \
    const int _cc = _c < 256 ? _c : 0;                                         \
    const float _t0 = Xt[(size_t)_cc * 4096 + bt0 + arow];                     \
    const float _t1 = Xt[(size_t)_cc * 4096 + bt0 + 128 + arow];               \
    S0 = (_c < 256) ? _t0 : 1.f;                                               \
    S1 = (_c < 256) ? _t1 : 1.f;                                               \
  }

#define PACK_AH(AV, H, S, BUF)                                                 \
  {                                                                            \
    const int _row = ((H) << 7) + arow;                                        \
    const int _sx = _row & 7;                                                  \
    f32x4 _m0 = (S) * AV[H][0], _m1 = (S) * AV[H][1];                          \
    f32x4 _m2 = (S) * AV[H][2], _m3 = (S) * AV[H][3];                          \
    *(bf16x8*)(&As[BUF][_row * 64 + ((((jq << 1) | 0) ^ _sx) << 3)]) =         \
        pack8(_m0, _m1);                                                       \
    *(bf16x8*)(&As[BUF][_row * 64 + ((((jq << 1) | 1) ^ _sx) << 3)]) =         \
        pack8(_m2, _m3);                                                       \
  }

#define STAGE_B(KT, BUF)                                                       \
  {                                                                            \
    const int _c = c0 + ((KT) >> 2);                                           \
    const int _jb = ((KT) & 3) << 6;                                           \
    _Pragma("unroll") for (int _e = 0; _e < 4; ++_e) {                         \
      const int _rbase = (wid << 5) + (_e << 3);                               \
      const int _orow = _rbase + (lane >> 3);                                  \
      const int _sl = (lane & 7) ^ (_orow & 7);                                \
      const unsigned short* _srcp =                                            \
          Bp + ((size_t)_c * 256 + _orow) * 256 + _jb + (_sl << 3);            \
      gload16(_srcp, &Bs[BUF][_rbase << 6]);                                   \
    }                                                                          \
  }

__global__ __launch_bounds__(512, 2) void gemm8(
    const float* __restrict__ X, const float* __restrict__ Xa,
    const float* __restrict__ Xt, const unsigned short* __restrict__ Bp,
    float* __restrict__ P) {
  __shared__ __align__(16) unsigned short As[2][256 * 64];
  __shared__ __align__(16) unsigned short Bs[2][256 * 64];

  const int tid = threadIdx.x;
  const int nwg = gridDim.x;
  const int S = nwg >> 4;

  // bijective XCD-cluster swizzle: consecutive w share a slice on one XCD
  const int rid = blockIdx.x;
  const int qx = nwg >> 3, rx = nwg & 7;
  const int xcd = rid & 7, sidx = rid >> 3;
  const int w = (xcd < rx ? xcd * (qx + 1) : rx * (qx + 1) + (xcd - rx) * qx) + sidx;
  const int bz = w >> 4, bx = w & 15;
  const int bt0 = bx << 8;

  const int q2 = 258 / S, r2 = 258 % S;
  const int c0 = bz * q2 + (bz < r2 ? bz : r2);
  const int ccnt = q2 + (bz < r2 ? 1 : 0);
  const int nKt = ccnt << 2;  // BK=64 tiles (multiple of 4)

  const int wid = tid >> 6, lane = tid & 63;
  const int wm = wid >> 2, wn = wid & 3;
  const int l15 = lane & 15, lg = lane >> 4;
  const int arow = tid >> 2, jq = tid & 3;  // A rows: 4 threads/row

  f32x4 acc[8][4] = {};
  f32x4 av0[2][4], av1[2][4];
  bf16x8 bfr[4];
  float sA0, sA1, sB0, sB1, sP0, sP1;

  // ---- prologue: stage kt=0 fully; preload av0 = av(1)
  LOAD_S(0, sP0, sP1);
  STAGE_B(0, 0);
  ISSUE_A(0, av1);
  ISSUE_A(1, av0);
  PACK_AH(av1, 0, sP0, 0);
  PACK_AH(av1, 1, sP1, 0);
  asm volatile("s_waitcnt vmcnt(8)" ::: "memory");  // B(0) drained; av0 in flight
  __syncthreads();

  // ---- main loop: 2 K-tiles / iteration, 8 phases
  for (int kt = 0; kt < nKt; kt += 2) {
    PHASE(0, 0, 0, 1,
          { LOAD_S(kt + 1, sA0, sA1); LOAD_S(kt + 2, sB0, sB1); STAGE_B(kt + 1, 1); },
          {});
    PHASE(0, 1, 0, 0, { ISSUE_A(kt + 2, av1); }, {});
    PHASE(0, 0, 1, 1, { PACK_AH(av0, 0, sA0, 1); }, {});
    PHASE(0, 1, 1, 0, { PACK_AH(av0, 1, sA1, 1); },
          { asm volatile("s_waitcnt vmcnt(8)" ::: "memory"); });
    PHASE(1, 0, 0, 1, { STAGE_B(kt + 2, 0); ISSUE_A(kt + 3, av0); }, {});
    PHASE(1, 1, 0, 0, { PACK_AH(av1, 0, sB0, 0); }, {});
    PHASE(1, 0, 1, 1, { PACK_AH(av1, 1, sB1, 0); }, {});
    PHASE(1, 1, 1, 0, {},
          { asm volatile("s_waitcnt vmcnt(8)" ::: "memory"); });
  }

  // ---- epilogue: C layout col = lane&15, row = (lane>>4)*4 + reg
  float* pp = P + ((size_t)bz << 20);
#pragma unroll
  for (int fm = 0; fm < 8; ++fm) {
    const int row = bt0 + (wm << 7) + (fm << 4) + (lg << 2);
#pragma unroll
    for (int fn = 0; fn < 4; ++fn) {
      const int col = (wn << 6) + (fn << 4) + l15;
#pragma unroll
      for (int e = 0; e < 4; ++e)
        pp[(size_t)(row + e) * 256 + col] = acc[fm][fn][e];
    }
  }
}

// ---- reduce: sum S partial slices + bias + W[o,0]
__global__ void reduce_k(const float* __restrict__ P, const float* __restrict__ W,
                         const float* __restrict__ b, float* __restrict__ out,
                         int nsl) {
  const int idx = blockIdx.x * 256 + threadIdx.x;
  const int o = idx & 255;
  float v = b[o] + W[(size_t)o * DI];
  for (int s = 0; s < nsl; ++s) v += P[idx + (size_t)s * 1048576];
  out[idx] = v;
}

// ================= fallback path (tiny ws): R2 proven kernels ================
__global__ void init_k(const float* __restrict__ W, const float* __restrict__ b,
                       float* __restrict__ out) {
  const int idx = blockIdx.x * 256 + threadIdx.x;
  const int o = idx & 255;
  out[idx] = b[o] + W[(size_t)o * DI];
}

__global__ __launch_bounds__(256, 4) void gemm_fb(
    const float* __restrict__ X, const float* __restrict__ Xa,
    const float* __restrict__ W, float* __restrict__ Out) {
  __shared__ __align__(16) unsigned short As[128 * 64];
  __shared__ __align__(16) unsigned short Bs[128 * 64];
  const int tid = threadIdx.x;
  const int bx = blockIdx.x, by = blockIdx.y, bz = blockIdx.z;
  const int S = gridDim.z;
  const int bt0 = bx << 7, o0 = by << 7;
  const int q = 258 / S, r = 258 % S;
  const int c0 = bz * q + (bz < r ? bz : r);
  const int ccnt = q + (bz < r ? 1 : 0);
  const int nK = ccnt << 2;
  const int wid = tid >> 6, lane = tid & 63;
  const int wr = (wid >> 1) << 6, wc = (wid & 1) << 6;
  const int ar = tid >> 1;
  const int ah = (tid & 1) << 5;
  const float* xrow = X + (size_t)(bt0 + ar) * 256;
  const float* varow = Xa + (size_t)(bt0 + ar) * 256;
  f32x4 acc[4][4] = {};
  for (int kt = 0; kt < nK; ++kt) {
    const int c = c0 + (kt >> 2);
    const int j0 = (kt & 3) << 6;
    __syncthreads();
    {
      const float* vs = (c == 257) ? xrow : varow;
      float s = 1.0f;
      if (c < 256) s = xrow[c];
      const f32x4* vp = (const f32x4*)(vs + j0 + ah);
      f32x4 v[8];
#pragma unroll
      for (int qq = 0; qq < 8; ++qq) v[qq] = vp[qq];
      unsigned short* aw = As + ar * 64;
      const int sl0 = ah >> 3, sx = ar & 7;
#pragma unroll
      for (int w = 0; w < 4; ++w) {
        bf16x8 pk;
#pragma unroll
        for (int e = 0; e < 8; ++e)
          pk[e] = (short)f2b(s * v[w * 2 + (e >> 2)][e & 3]);
        *(bf16x8*)(aw + (((sl0 + w) ^ sx) << 3)) = pk;
      }
    }
    {
      const int orow = tid >> 1;
      const int jh = (tid & 1) << 5;
      const float* wrow = W + (size_t)(o0 + orow) * DI;
      float tmp[32];
      if (c < 256) {
        const int bse = (c + 1) * 257 + 1 + j0 + jh;
#pragma unroll
        for (int i = 0; i < 32; ++i) tmp[i] = wrow[bse + i];
      } else if (c == 256) {
        const int bse = 1 + j0 + jh;
#pragma unroll
        for (int i = 0; i < 32; ++i) tmp[i] = wrow[bse + i];
      } else {
#pragma unroll
        for (int i = 0; i < 32; ++i) tmp[i] = wrow[(j0 + jh + i + 1) * 257];
      }
      unsigned short* bw = Bs + orow * 64;
      const int sl0 = jh >> 3, sx = orow & 7;
#pragma unroll
      for (int w = 0; w < 4; ++w) {
        bf16x8 pk;
#pragma unroll
        for (int e = 0; e < 8; ++e) pk[e] = (short)f2b(tmp[w * 8 + e]);
        *(bf16x8*)(bw + (((sl0 + w) ^ sx) << 3)) = pk;
      }
    }
    __syncthreads();
#pragma unroll
    for (int kk = 0; kk < 2; ++kk) {
      const int kslot = (kk << 2) + (lane >> 4);
      bf16x8 af[4], bfr2[4];
#pragma unroll
      for (int fm = 0; fm < 4; ++fm) {
        const int row = wr + (fm << 4) + (lane & 15);
        af[fm] = *(const bf16x8*)(As + row * 64 + ((kslot ^ (row & 7)) << 3));
      }
#pragma unroll
      for (int fn = 0; fn < 4; ++fn) {
        const int row = wc + (fn << 4) + (lane & 15);
        bfr2[fn] = *(const bf16x8*)(Bs + row * 64 + ((kslot ^ (row & 7)) << 3));
      }
#pragma unroll
      for (int fm = 0; fm < 4; ++fm)
#pragma unroll
        for (int fn = 0; fn < 4; ++fn)
          acc[fm][fn] = __builtin_amdgcn_mfma_f32_16x16x32_bf16(
              af[fm], bfr2[fn], acc[fm][fn], 0, 0, 0);
    }
  }
  const int r0 = (lane >> 4) << 2;
  const int cl = lane & 15;
#pragma unroll
  for (int fm = 0; fm < 4; ++fm) {
    const int row = bt0 + wr + (fm << 4) + r0;
#pragma unroll
    for (int fn = 0; fn < 4; ++fn) {
      const int col = o0 + wc + (fn << 4) + cl;
#pragma unroll
      for (int rr = 0; rr < 4; ++rr)
        atomicAdd(Out + (size_t)(row + rr) * 256 + col, acc[fm][fn][rr]);
    }
  }
}

extern "C" void kernel_launch(void* const* d_in, const int* in_sizes, int n_in,
                              void* d_out, int out_size, void* d_ws, size_t ws_size,
                              hipStream_t stream) {
  const float* X  = (const float*)d_in[0];
  const float* Xa = (const float*)d_in[1];
  const float* W  = (const float*)d_in[2];
  const float* b  = (const float*)d_in[3];
  float* out = (float*)d_out;

  const size_t WBF_SZ = (size_t)258 * 256 * 256 * 2;  // 33,816,576 B
  const size_t XT_SZ  = (size_t)256 * 4096 * 4;       //  4,194,304 B
  const size_t PART1  = (size_t)4096 * 256 * 4;       //  4 MiB per slice

  int S = 0;
  if (ws_size > WBF_SZ + XT_SZ) {
    size_t fit = (ws_size - WBF_SZ - XT_SZ) / PART1;
    S = (int)(fit < 16 ? fit : 16);
  }

  if (S >= 2) {
    unsigned short* Bp = (unsigned short*)d_ws;
    float* Xt = (float*)((char*)d_ws + WBF_SZ);
    float* P  = (float*)((char*)d_ws + WBF_SZ + XT_SZ);
    prep_w<<<dim3(258, 64), 256, 0, stream>>>(W, Bp);
    prep_xt<<<dim3(128, 8), dim3(32, 8), 0, stream>>>(X, Xt);
    gemm8<<<dim3(16 * S), 512, 0, stream>>>(X, Xa, Xt, Bp, P);
    reduce_k<<<4096, 256, 0, stream>>>(P, W, b, out, S);
  } else {
    init_k<<<4096, 256, 0, stream>>>(W, b, out);
    gemm_fb<<<dim3(32, 2, 4), 256, 0, stream>>>(X, Xa, W, out);
  }
}

// Round 6
// 175.342 us; speedup vs baseline: 5.1017x; 1.4504x over previous
//
#include <hip/hip_runtime.h>
#include <hip/hip_bf16.h>

// out[bt,o] = b[o] + sum_{i,j} Xa[bt,i]*Xb[bt,j]*W[o, i*257+j], Xa=[1,X], Xb=[1,X_aux]
// Chunk decomposition (c in [0,258)):
//   c<256 : contrib = X[r,c] * sum_j Xb[r,j]*Bp[c][o][j]
//   c=256 : contrib =          sum_j Xb[r,j]*Bp[256][o][j]
//   c=257 : contrib =          sum_j X [r,j]*Bp[257][o][j]
// k=0 corner (W[o,0]) folded into reduce with bias.
//
// R6: scale-after-MFMA with chunk-invariant A. As = raw bf16 X_aux packed
// ONCE per block (64KB static LDS, 16-slot XOR swizzle). Per chunk c:
// t[rg][fn] accumulates 8 k-windows of MFMA, then acc += X[r,c]*t (f32).
// B via global_load_lds dbuf (linear dest, pre-swizzled source). One
// __syncthreads per K-tile. Grid 256 = 8 slices x 32 m-tiles (1 block/CU),
// slice pinned to XCD by rid&7. Slice 7: c in [225,257) then repack As=X
// for c=257.

#define DI 66049

typedef __attribute__((ext_vector_type(8))) short bf16x8;
typedef __attribute__((ext_vector_type(4))) float f32x4;

__device__ __forceinline__ unsigned short f2b(float f) {
  union { __hip_bfloat16 h; unsigned short u; } cv;
  cv.h = __float2bfloat16(f);
  return cv.u;
}

__device__ __forceinline__ bf16x8 pack8(f32x4 lo, f32x4 hi) {
  bf16x8 r;
  r[0] = (short)f2b(lo[0]); r[1] = (short)f2b(lo[1]);
  r[2] = (short)f2b(lo[2]); r[3] = (short)f2b(lo[3]);
  r[4] = (short)f2b(hi[0]); r[5] = (short)f2b(hi[1]);
  r[6] = (short)f2b(hi[2]); r[7] = (short)f2b(hi[3]);
  return r;
}

__device__ __forceinline__ void gload16(const void* g, void* l) {
  __builtin_amdgcn_global_load_lds(
      (const __attribute__((address_space(1))) unsigned int*)g,
      (__attribute__((address_space(3))) unsigned int*)l, 16, 0, 0);
}

// ---- prep: gather W (f32) into bf16 Bp[c][o][j] (linear), c in [0,258)
__global__ void prep_w(const float* __restrict__ W, unsigned short* __restrict__ Bp) {
  const int c = blockIdx.x;
  const int o = (blockIdx.y << 2) + (threadIdx.x >> 6);
  const int j = (threadIdx.x & 63) << 2;
  const float* wrow = W + (size_t)o * DI;
  float v0, v1, v2, v3;
  if (c < 256) {
    const int bse = (c + 1) * 257 + 1 + j;
    v0 = wrow[bse]; v1 = wrow[bse + 1]; v2 = wrow[bse + 2]; v3 = wrow[bse + 3];
  } else if (c == 256) {
    const int bse = 1 + j;
    v0 = wrow[bse]; v1 = wrow[bse + 1]; v2 = wrow[bse + 2]; v3 = wrow[bse + 3];
  } else {
    v0 = wrow[(j + 1) * 257]; v1 = wrow[(j + 2) * 257];
    v2 = wrow[(j + 3) * 257]; v3 = wrow[(j + 4) * 257];
  }
  unsigned short* dst = Bp + (((size_t)c << 8) + o) * 256 + j;
  const unsigned int lo = (unsigned int)f2b(v0) | ((unsigned int)f2b(v1) << 16);
  const unsigned int hi = (unsigned int)f2b(v2) | ((unsigned int)f2b(v3) << 16);
  *(uint2*)dst = make_uint2(lo, hi);
}

// ---- prep: Xt[c][bt] = X[bt][c]  (f32 transpose for coalesced scale loads)
__global__ void prep_xt(const float* __restrict__ X, float* __restrict__ Xt) {
  __shared__ float t[32][33];
  const int tx = threadIdx.x, ty = threadIdx.y;
  const int bt0 = blockIdx.x << 5, c0 = blockIdx.y << 5;
#pragma unroll
  for (int k = 0; k < 4; ++k) {
    const int row = (ty << 2) + k;
    t[row][tx] = X[(size_t)(bt0 + row) * 256 + c0 + tx];
  }
  __syncthreads();
#pragma unroll
  for (int k = 0; k < 4; ++k) {
    const int row = (ty << 2) + k;
    Xt[(size_t)(c0 + row) * 4096 + bt0 + tx] = t[tx][row];
  }
}

// pack As[128][256] bf16 from SRC rows [bt0,bt0+128), 16-slot XOR swizzle
#define PACK_AS(SRC)                                                           \
  {                                                                            \
    const int _row = tid >> 2, _q = tid & 3;                                   \
    const float* _rp = (SRC) + (size_t)(bt0 + _row) * 256 + (_q << 6);         \
    const int _sx = _row & 15;                                                 \
    _Pragma("unroll") for (int _w = 0; _w < 8; ++_w) {                         \
      f32x4 _lo = *(const f32x4*)(_rp + (_w << 3));                            \
      f32x4 _hi = *(const f32x4*)(_rp + (_w << 3) + 4);                        \
      const int _slot = (_q << 3) + _w;                                        \
      *(bf16x8*)(&As[_row * 256 + ((_slot ^ _sx) << 3)]) = pack8(_lo, _hi);    \
    }                                                                          \
  }

// stage one B K-tile (c, jb) into Bs[BUF]: 4 x gload16/thread, linear dest,
// pre-swizzled source column (8-slot XOR, proven 0-conflict)
#define STAGE(C, JB, BUF)                                                      \
  {                                                                            \
    _Pragma("unroll") for (int _e = 0; _e < 4; ++_e) {                         \
      const int _idx = (_e << 9) | tid;                                        \
      const int _row = _idx >> 3;                                              \
      const int _sl = (_idx & 7) ^ (_row & 7);                                 \
      gload16(Bp + ((size_t)(C) * 256 + _row) * 256 + (JB) + (_sl << 3),       \
              &Bs[BUF][(size_t)_idx << 3]);                                    \
    }                                                                          \
  }

// one K-tile: stage next, 8 B-frag reads, 4x(2 A-frag reads + 8 MFMA), sync
#define KTBODY(K4, CUR, CN, JBN)                                               \
  {                                                                            \
    STAGE(CN, JBN, (CUR) ^ 1);                                                 \
    bf16x8 bf0[4], bf1[4];                                                     \
    _Pragma("unroll") for (int fn = 0; fn < 4; ++fn) {                         \
      const int _rb = (wn << 6) + (fn << 4) + l15;                             \
      const int _rx = _rb & 7;                                                 \
      bf0[fn] = *(const bf16x8*)(&Bs[CUR][_rb * 64 + ((lg ^ _rx) << 3)]);      \
      bf1[fn] = *(const bf16x8*)(&Bs[CUR][_rb * 64 + (((4 + lg) ^ _rx) << 3)]);\
    }                                                                          \
    _Pragma("unroll") for (int rg = 0; rg < 4; ++rg) {                         \
      const int _ra = wr + (rg << 4) + l15;                                    \
      const int _sx = _ra & 15;                                                \
      const int _sb = (K4) << 3;                                               \
      bf16x8 _a0 =                                                             \
          *(const bf16x8*)(&As[_ra * 256 + (((_sb + lg) ^ _sx) << 3)]);        \
      bf16x8 _a1 =                                                             \
          *(const bf16x8*)(&As[_ra * 256 + (((_sb + 4 + lg) ^ _sx) << 3)]);    \
      _Pragma("unroll") for (int fn = 0; fn < 4; ++fn) {                       \
        t[rg][fn] = __builtin_amdgcn_mfma_f32_16x16x32_bf16(_a0, bf0[fn],      \
                                                            t[rg][fn], 0, 0, 0); \
        t[rg][fn] = __builtin_amdgcn_mfma_f32_16x16x32_bf16(_a1, bf1[fn],      \
                                                            t[rg][fn], 0, 0, 0); \
      }                                                                        \
    }                                                                          \
    __syncthreads();                                                           \
  }

__global__ __launch_bounds__(512, 2) void gemm_r6(
    const float* __restrict__ X, const float* __restrict__ Xb,
    const float* __restrict__ Xt, const unsigned short* __restrict__ Bp,
    float* __restrict__ P) {
  __shared__ __align__(16) unsigned short As[128 * 256];     // 64 KB static A
  __shared__ __align__(16) unsigned short Bs[2][256 * 64];   // 2 x 32 KB dbuf

  const int tid = threadIdx.x;
  const int rid = blockIdx.x;
  const int slice = rid & 7;   // slice pinned to XCD (rid%8 round-robin)
  const int bx = rid >> 3;
  const int bt0 = bx << 7;
  const bool is7 = (slice == 7);
  // slices 0..6 split c in [0,225): 33,32,32,32,32,32,32 ; slice 7: [225,257)+{257}
  const int c0 = is7 ? 225 : slice * 32 + (slice ? 1 : 0);
  const int nCh = (slice == 0 || is7) ? 33 : 32;

  const int wid = tid >> 6, lane = tid & 63;
  const int wm = wid >> 2, wn = wid & 3;  // 2 (bt) x 4 (o) waves
  const int wr = wm << 6;
  const int l15 = lane & 15, lg = lane >> 4;

  PACK_AS(Xb);
  STAGE(c0, 0, 0);
  __syncthreads();

  f32x4 acc[4][4] = {};
  int cur = 0;

  for (int ci = 0; ci < nCh; ++ci) {
    const int c = is7 ? (ci < 32 ? 225 + ci : 257) : c0 + ci;

    // scales for this chunk (f32; rows match C-layout rows)
    f32x4 s4[4];
    if (c < 256) {
      const float* sp = Xt + (size_t)c * 4096 + bt0 + wr + (lg << 2);
#pragma unroll
      for (int rg = 0; rg < 4; ++rg) s4[rg] = *(const f32x4*)(sp + (rg << 4));
    } else {
#pragma unroll
      for (int rg = 0; rg < 4; ++rg) s4[rg] = (f32x4){1.f, 1.f, 1.f, 1.f};
    }

    f32x4 t[4][4] = {};
#pragma unroll
    for (int k4 = 0; k4 < 4; ++k4) {
      int nk = (ci << 2) + k4 + 1;
      const int nkmax = (nCh << 2) - 1;
      if (nk > nkmax) nk = nkmax;
      const int nci = nk >> 2;
      const int cn = is7 ? (nci < 32 ? 225 + nci : 257) : c0 + nci;
      const int jbn = (nk & 3) << 6;
      KTBODY(k4, cur, cn, jbn);
      cur ^= 1;
    }

#pragma unroll
    for (int rg = 0; rg < 4; ++rg)
#pragma unroll
      for (int fn = 0; fn < 4; ++fn) acc[rg][fn] += s4[rg] * t[rg][fn];

    if (is7 && ci == 31) {  // switch A-operand to X for the c=257 chunk
      __syncthreads();
      PACK_AS(X);
      __syncthreads();
    }
  }

  // ---- epilogue: C layout col = lane&15, row = (lane>>4)*4 + reg
  float* pp = P + ((size_t)slice << 20);
#pragma unroll
  for (int rg = 0; rg < 4; ++rg) {
    const int row = bt0 + wr + (rg << 4) + (lg << 2);
#pragma unroll
    for (int fn = 0; fn < 4; ++fn) {
      const int col = (wn << 6) + (fn << 4) + l15;
#pragma unroll
      for (int e = 0; e < 4; ++e)
        pp[(size_t)(row + e) * 256 + col] = acc[rg][fn][e];
    }
  }
}

// ---- reduce: sum 8 partial slices + bias + W[o,0]
__global__ void reduce_k(const float* __restrict__ P, const float* __restrict__ W,
                         const float* __restrict__ b, float* __restrict__ out,
                         int nsl) {
  const int idx = blockIdx.x * 256 + threadIdx.x;
  const int o = idx & 255;
  float v = b[o] + W[(size_t)o * DI];
  for (int s = 0; s < nsl; ++s) v += P[idx + (size_t)s * 1048576];
  out[idx] = v;
}

// ================= fallback path (tiny ws): R2 proven kernels ================
__global__ void init_k(const float* __restrict__ W, const float* __restrict__ b,
                       float* __restrict__ out) {
  const int idx = blockIdx.x * 256 + threadIdx.x;
  const int o = idx & 255;
  out[idx] = b[o] + W[(size_t)o * DI];
}

__global__ __launch_bounds__(256, 4) void gemm_fb(
    const float* __restrict__ X, const float* __restrict__ Xa,
    const float* __restrict__ W, float* __restrict__ Out) {
  __shared__ __align__(16) unsigned short As[128 * 64];
  __shared__ __align__(16) unsigned short Bs[128 * 64];
  const int tid = threadIdx.x;
  const int bx = blockIdx.x, by = blockIdx.y, bz = blockIdx.z;
  const int S = gridDim.z;
  const int bt0 = bx << 7, o0 = by << 7;
  const int q = 258 / S, r = 258 % S;
  const int c0 = bz * q + (bz < r ? bz : r);
  const int ccnt = q + (bz < r ? 1 : 0);
  const int nK = ccnt << 2;
  const int wid = tid >> 6, lane = tid & 63;
  const int wr = (wid >> 1) << 6, wc = (wid & 1) << 6;
  const int ar = tid >> 1;
  const int ah = (tid & 1) << 5;
  const float* xrow = X + (size_t)(bt0 + ar) * 256;
  const float* varow = Xa + (size_t)(bt0 + ar) * 256;
  f32x4 acc[4][4] = {};
  for (int kt = 0; kt < nK; ++kt) {
    const int c = c0 + (kt >> 2);
    const int j0 = (kt & 3) << 6;
    __syncthreads();
    {
      const float* vs = (c == 257) ? xrow : varow;
      float s = 1.0f;
      if (c < 256) s = xrow[c];
      const f32x4* vp = (const f32x4*)(vs + j0 + ah);
      f32x4 v[8];
#pragma unroll
      for (int qq = 0; qq < 8; ++qq) v[qq] = vp[qq];
      unsigned short* aw = As + ar * 64;
      const int sl0 = ah >> 3, sx = ar & 7;
#pragma unroll
      for (int w = 0; w < 4; ++w) {
        bf16x8 pk;
#pragma unroll
        for (int e = 0; e < 8; ++e)
          pk[e] = (short)f2b(s * v[w * 2 + (e >> 2)][e & 3]);
        *(bf16x8*)(aw + (((sl0 + w) ^ sx) << 3)) = pk;
      }
    }
    {
      const int orow = tid >> 1;
      const int jh = (tid & 1) << 5;
      const float* wrow = W + (size_t)(o0 + orow) * DI;
      float tmp[32];
      if (c < 256) {
        const int bse = (c + 1) * 257 + 1 + j0 + jh;
#pragma unroll
        for (int i = 0; i < 32; ++i) tmp[i] = wrow[bse + i];
      } else if (c == 256) {
        const int bse = 1 + j0 + jh;
#pragma unroll
        for (int i = 0; i < 32; ++i) tmp[i] = wrow[bse + i];
      } else {
#pragma unroll
        for (int i = 0; i < 32; ++i) tmp[i] = wrow[(j0 + jh + i + 1) * 257];
      }
      unsigned short* bw = Bs + orow * 64;
      const int sl0 = jh >> 3, sx = orow & 7;
#pragma unroll
      for (int w = 0; w < 4; ++w) {
        bf16x8 pk;
#pragma unroll
        for (int e = 0; e < 8; ++e) pk[e] = (short)f2b(tmp[w * 8 + e]);
        *(bf16x8*)(bw + (((sl0 + w) ^ sx) << 3)) = pk;
      }
    }
    __syncthreads();
#pragma unroll
    for (int kk = 0; kk < 2; ++kk) {
      const int kslot = (kk << 2) + (lane >> 4);
      bf16x8 af[4], bfr2[4];
#pragma unroll
      for (int fm = 0; fm < 4; ++fm) {
        const int row = wr + (fm << 4) + (lane & 15);
        af[fm] = *(const bf16x8*)(As + row * 64 + ((kslot ^ (row & 7)) << 3));
      }
#pragma unroll
      for (int fn = 0; fn < 4; ++fn) {
        const int row = wc + (fn << 4) + (lane & 15);
        bfr2[fn] = *(const bf16x8*)(Bs + row * 64 + ((kslot ^ (row & 7)) << 3));
      }
#pragma unroll
      for (int fm = 0; fm < 4; ++fm)
#pragma unroll
        for (int fn = 0; fn < 4; ++fn)
          acc[fm][fn] = __builtin_amdgcn_mfma_f32_16x16x32_bf16(
              af[fm], bfr2[fn], acc[fm][fn], 0, 0, 0);
    }
  }
  const int r0 = (lane >> 4) << 2;
  const int cl = lane & 15;
#pragma unroll
  for (int fm = 0; fm < 4; ++fm) {
    const int row = bt0 + wr + (fm << 4) + r0;
#pragma unroll
    for (int fn = 0; fn < 4; ++fn) {
      const int col = o0 + wc + (fn << 4) + cl;
#pragma unroll
      for (int rr = 0; rr < 4; ++rr)
        atomicAdd(Out + (size_t)(row + rr) * 256 + col, acc[fm][fn][rr]);
    }
  }
}

extern "C" void kernel_launch(void* const* d_in, const int* in_sizes, int n_in,
                              void* d_out, int out_size, void* d_ws, size_t ws_size,
                              hipStream_t stream) {
  const float* X  = (const float*)d_in[0];
  const float* Xa = (const float*)d_in[1];
  const float* W  = (const float*)d_in[2];
  const float* b  = (const float*)d_in[3];
  float* out = (float*)d_out;

  const size_t WBF_SZ = (size_t)258 * 256 * 256 * 2;  // 33,816,576 B
  const size_t XT_SZ  = (size_t)256 * 4096 * 4;       //  4,194,304 B
  const size_t PART1  = (size_t)4096 * 256 * 4;       //  4 MiB per slice

  if (ws_size >= WBF_SZ + XT_SZ + 8 * PART1) {
    unsigned short* Bp = (unsigned short*)d_ws;
    float* Xt = (float*)((char*)d_ws + WBF_SZ);
    float* P  = (float*)((char*)d_ws + WBF_SZ + XT_SZ);
    prep_w<<<dim3(258, 64), 256, 0, stream>>>(W, Bp);
    prep_xt<<<dim3(128, 8), dim3(32, 8), 0, stream>>>(X, Xt);
    gemm_r6<<<dim3(256), 512, 0, stream>>>(X, Xa, Xt, Bp, P);
    reduce_k<<<4096, 256, 0, stream>>>(P, W, b, out, 8);
  } else {
    init_k<<<4096, 256, 0, stream>>>(W, b, out);
    gemm_fb<<<dim3(32, 2, 4), 256, 0, stream>>>(X, Xa, W, out);
  }
}